// Round 1
// baseline (459.861 us; speedup 1.0000x reference)
//
#include <hip/hip_runtime.h>

typedef unsigned short u16;
typedef __attribute__((ext_vector_type(8))) short short8;
typedef __attribute__((ext_vector_type(4))) float f32x4;

__device__ __forceinline__ u16 f32_to_bf16(float f) {
  unsigned int u = __builtin_bit_cast(unsigned int, f);
  u += 0x7fffu + ((u >> 16) & 1u);  // round-to-nearest-even
  return (u16)(u >> 16);
}

// ---------------- x (fp32) -> bf16, 8 elems/thread ----------------
__global__ __launch_bounds__(256) void cvt_bf16_kernel(const float* __restrict__ in,
                                                       u16* __restrict__ out, int n8) {
  int i = blockIdx.x * 256 + threadIdx.x;
  if (i >= n8) return;
  const float4* p = (const float4*)in + (size_t)i * 2;
  float4 a = p[0], b = p[1];
  int4 v;
  v.x = (int)f32_to_bf16(a.x) | ((int)f32_to_bf16(a.y) << 16);
  v.y = (int)f32_to_bf16(a.z) | ((int)f32_to_bf16(a.w) << 16);
  v.z = (int)f32_to_bf16(b.x) | ((int)f32_to_bf16(b.y) << 16);
  v.w = (int)f32_to_bf16(b.z) | ((int)f32_to_bf16(b.w) << 16);
  *(int4*)(out + (size_t)i * 8) = v;
}

// ------------- fp32 [R][C] -> bf16 [C][R] (weights, one-time) -------------
__global__ __launch_bounds__(256) void transpose_bf16_kernel(const float* __restrict__ in,
                                                             u16* __restrict__ out, int R, int C) {
  __shared__ u16 tile[32][33];
  int tx = threadIdx.x & 31, ty = threadIdx.x >> 5;  // 32 x 8
  int c0 = blockIdx.x * 32, r0 = blockIdx.y * 32;
#pragma unroll
  for (int j = 0; j < 32; j += 8)
    tile[ty + j][tx] = f32_to_bf16(in[(size_t)(r0 + ty + j) * C + c0 + tx]);
  __syncthreads();
#pragma unroll
  for (int j = 0; j < 32; j += 8)
    out[(size_t)(c0 + ty + j) * R + r0 + tx] = tile[tx][ty + j];
}

// ---------------- bf16 GEMM: C = A[M][K] * Bt[N][K]^T + bias ----------------
// MODE 0: scatter to Q/K/V bf16 [B=4][H=16][S=2048][64]
// MODE 1: fp32 out [M][N]
template <int MODE>
__global__ __launch_bounds__(256) void gemm_kernel(
    const u16* __restrict__ A, const u16* __restrict__ Bt, const float* __restrict__ bias,
    float* __restrict__ outf, u16* __restrict__ qo, u16* __restrict__ ko, u16* __restrict__ vo,
    int M, int N, int K) {
  __shared__ u16 Al[128][40];  // stride 40 elems = 80 B (16B-aligned rows)
  __shared__ u16 Bl[128][40];
  int tid = threadIdx.x;
  int bm = blockIdx.y * 128, bn = blockIdx.x * 128;
  int lane = tid & 63, wid = tid >> 6;
  int lo = lane & 15, hi = lane >> 4;
  int wm = (wid >> 1) * 64, wn = (wid & 1) * 64;
  int r1 = tid >> 2, c1 = (tid & 3) * 8;  // staging: 2 x 16B per thread per tile
  const u16* Arow1 = A + (size_t)(bm + r1) * K + c1;
  const u16* Arow2 = A + (size_t)(bm + r1 + 64) * K + c1;
  const u16* Brow1 = Bt + (size_t)(bn + r1) * K + c1;
  const u16* Brow2 = Bt + (size_t)(bn + r1 + 64) * K + c1;

  f32x4 acc[4][4] = {};
  for (int k0 = 0; k0 < K; k0 += 32) {
    __syncthreads();
    *(int4*)&Al[r1][c1]      = *(const int4*)(Arow1 + k0);
    *(int4*)&Al[r1 + 64][c1] = *(const int4*)(Arow2 + k0);
    *(int4*)&Bl[r1][c1]      = *(const int4*)(Brow1 + k0);
    *(int4*)&Bl[r1 + 64][c1] = *(const int4*)(Brow2 + k0);
    __syncthreads();
    short8 af[4], bfr[4];
#pragma unroll
    for (int mi = 0; mi < 4; ++mi) af[mi] = *(const short8*)&Al[wm + mi * 16 + lo][hi * 8];
#pragma unroll
    for (int ni = 0; ni < 4; ++ni) bfr[ni] = *(const short8*)&Bl[wn + ni * 16 + lo][hi * 8];
#pragma unroll
    for (int mi = 0; mi < 4; ++mi)
#pragma unroll
      for (int ni = 0; ni < 4; ++ni)
        acc[mi][ni] = __builtin_amdgcn_mfma_f32_16x16x32_bf16(af[mi], bfr[ni], acc[mi][ni], 0, 0, 0);
  }

#pragma unroll
  for (int mi = 0; mi < 4; ++mi)
#pragma unroll
    for (int ni = 0; ni < 4; ++ni) {
      int col = bn + wn + ni * 16 + lo;
      float bv = bias[col];
#pragma unroll
      for (int r = 0; r < 4; ++r) {
        int row = bm + wm + mi * 16 + hi * 4 + r;
        float val = acc[mi][ni][r] + bv;
        if (MODE == 1) {
          outf[(size_t)row * N + col] = val;
        } else {
          int part = col >> 10, rem = col & 1023;
          int h = rem >> 6, d = rem & 63;
          int b = row >> 11, s = row & 2047;
          u16* dst = (part == 0) ? qo : (part == 1) ? ko : vo;
          dst[(size_t)((b * 16 + h) * 2048 + s) * 64 + d] = f32_to_bf16(val);
        }
      }
    }
}

// ---------------- flash attention ----------------
// grid: (16 q-tiles, 64 bh). 256 thr = 4 waves; 128 q-rows/block, 32/wave; KV tile 64.
__global__ __launch_bounds__(256) void attn_kernel(const u16* __restrict__ Qg,
                                                   const u16* __restrict__ Kg,
                                                   const u16* __restrict__ Vg,
                                                   u16* __restrict__ ctx) {
  __shared__ u16 Qs[128][72];      // [q][dh]
  __shared__ u16 Ks[64][72];       // [key][dh]
  __shared__ u16 Vts[64][72];      // [dh][key]  (transposed for B-frag reads)
  __shared__ u16 Ps[4][32][72];    // per-wave P round-trip [q][key]
  int tid = threadIdx.x;
  int qb = blockIdx.x, bh = blockIdx.y;
  const u16* Qh = Qg + (size_t)bh * 2048 * 64;
  const u16* Kh = Kg + (size_t)bh * 2048 * 64;
  const u16* Vh = Vg + (size_t)bh * 2048 * 64;
  int lane = tid & 63, wid = tid >> 6;
  int lo = lane & 15, hi = lane >> 4;

  // stage Q tile (coalesced), then pull A-fragments into registers once
#pragma unroll
  for (int i = 0; i < 4; ++i) {
    int v = tid + i * 256;
    int r = v >> 3, c = (v & 7) * 8;
    *(int4*)&Qs[r][c] = *(const int4*)&Qh[(size_t)(qb * 128 + r) * 64 + c];
  }
  __syncthreads();
  short8 qf[2][2];
#pragma unroll
  for (int mi = 0; mi < 2; ++mi)
#pragma unroll
    for (int kk = 0; kk < 2; ++kk)
      qf[mi][kk] = *(const short8*)&Qs[wid * 32 + mi * 16 + lo][kk * 32 + hi * 8];

  f32x4 o[2][4] = {};
  float mst[2][4], lst[2][4];
#pragma unroll
  for (int mi = 0; mi < 2; ++mi)
#pragma unroll
    for (int r = 0; r < 4; ++r) { mst[mi][r] = -1e30f; lst[mi][r] = 0.f; }

  for (int kt = 0; kt < 32; ++kt) {
    __syncthreads();  // previous tile's reads done before overwrite
    // stage K (row-major) and V (transposed); consecutive lanes -> consecutive rows
#pragma unroll
    for (int i = 0; i < 2; ++i) {
      int t = tid + i * 256;
      int r = t & 63, c = ((t >> 6) & 7) * 8;
      *(int4*)&Ks[r][c] = *(const int4*)&Kh[(size_t)(kt * 64 + r) * 64 + c];
      int4 vv = *(const int4*)&Vh[(size_t)(kt * 64 + r) * 64 + c];
      const u16* vp = (const u16*)&vv;
#pragma unroll
      for (int j = 0; j < 8; ++j) Vts[c + j][r] = vp[j];
    }
    __syncthreads();

    // S = Q K^T  (per wave: 32 q-rows x 64 keys)
    f32x4 sa[2][4] = {};
#pragma unroll
    for (int kk = 0; kk < 2; ++kk) {
      short8 kf[4];
#pragma unroll
      for (int ni = 0; ni < 4; ++ni) kf[ni] = *(const short8*)&Ks[ni * 16 + lo][kk * 32 + hi * 8];
#pragma unroll
      for (int mi = 0; mi < 2; ++mi)
#pragma unroll
        for (int ni = 0; ni < 4; ++ni)
          sa[mi][ni] = __builtin_amdgcn_mfma_f32_16x16x32_bf16(qf[mi][kk], kf[ni], sa[mi][ni], 0, 0, 0);
    }
#pragma unroll
    for (int mi = 0; mi < 2; ++mi)
#pragma unroll
      for (int ni = 0; ni < 4; ++ni) sa[mi][ni] *= 0.125f;  // 1/sqrt(64)

    // online softmax (row reduce across 16 lanes of the same hi-group)
#pragma unroll
    for (int mi = 0; mi < 2; ++mi)
#pragma unroll
      for (int r = 0; r < 4; ++r) {
        float mx = fmaxf(fmaxf(sa[mi][0][r], sa[mi][1][r]), fmaxf(sa[mi][2][r], sa[mi][3][r]));
        mx = fmaxf(mx, __shfl_xor(mx, 1, 64));
        mx = fmaxf(mx, __shfl_xor(mx, 2, 64));
        mx = fmaxf(mx, __shfl_xor(mx, 4, 64));
        mx = fmaxf(mx, __shfl_xor(mx, 8, 64));
        float mold = mst[mi][r];
        float mnew = fmaxf(mold, mx);
        float corr = __expf(mold - mnew);
        float rs = 0.f;
#pragma unroll
        for (int ni = 0; ni < 4; ++ni) {
          float p = __expf(sa[mi][ni][r] - mnew);
          sa[mi][ni][r] = p;
          rs += p;
        }
        rs += __shfl_xor(rs, 1, 64);
        rs += __shfl_xor(rs, 2, 64);
        rs += __shfl_xor(rs, 4, 64);
        rs += __shfl_xor(rs, 8, 64);
        lst[mi][r] = lst[mi][r] * corr + rs;
        mst[mi][r] = mnew;
#pragma unroll
        for (int di = 0; di < 4; ++di) o[mi][di][r] *= corr;
      }

    // P: C-layout regs -> bf16 in LDS (own wave region) -> A-layout frags
#pragma unroll
    for (int mi = 0; mi < 2; ++mi)
#pragma unroll
      for (int ni = 0; ni < 4; ++ni)
#pragma unroll
        for (int r = 0; r < 4; ++r)
          Ps[wid][mi * 16 + hi * 4 + r][ni * 16 + lo] = f32_to_bf16(sa[mi][ni][r]);
    asm volatile("s_waitcnt lgkmcnt(0)" ::: "memory");
    __builtin_amdgcn_sched_barrier(0);

    // O += P V
#pragma unroll
    for (int kk2 = 0; kk2 < 2; ++kk2) {
      short8 pf[2], vf[4];
#pragma unroll
      for (int mi = 0; mi < 2; ++mi) pf[mi] = *(const short8*)&Ps[wid][mi * 16 + lo][kk2 * 32 + hi * 8];
#pragma unroll
      for (int di = 0; di < 4; ++di) vf[di] = *(const short8*)&Vts[di * 16 + lo][kk2 * 32 + hi * 8];
#pragma unroll
      for (int mi = 0; mi < 2; ++mi)
#pragma unroll
        for (int di = 0; di < 4; ++di)
          o[mi][di] = __builtin_amdgcn_mfma_f32_16x16x32_bf16(pf[mi], vf[di], o[mi][di], 0, 0, 0);
    }
  }

  // epilogue: normalize, write ctx bf16 [B*S][1024]
  int b = bh >> 4, h = bh & 15;
#pragma unroll
  for (int mi = 0; mi < 2; ++mi)
#pragma unroll
    for (int di = 0; di < 4; ++di)
#pragma unroll
      for (int r = 0; r < 4; ++r) {
        int srow = qb * 128 + wid * 32 + mi * 16 + hi * 4 + r;
        int d = di * 16 + lo;
        float val = o[mi][di][r] / lst[mi][r];
        ctx[(size_t)(b * 2048 + srow) * 1024 + h * 64 + d] = f32_to_bf16(val);
      }
}

extern "C" void kernel_launch(void* const* d_in, const int* in_sizes, int n_in,
                              void* d_out, int out_size, void* d_ws, size_t ws_size,
                              hipStream_t stream) {
  const float* x      = (const float*)d_in[0];
  const float* w_qkv  = (const float*)d_in[1];
  const float* b_qkv  = (const float*)d_in[2];
  const float* w_proj = (const float*)d_in[3];
  const float* b_proj = (const float*)d_in[4];
  float* out = (float*)d_out;
  char* ws = (char*)d_ws;

  // ws layout (40 MB): xb/ctx alias 16.8M | wqkvT 6.3M | wprojT 2.1M | V 16.8M
  u16* xb     = (u16*)(ws);              // x bf16 [8192][1024]; later reused as ctx
  u16* wqkvT  = (u16*)(ws + 16777216);   // [3072][1024]
  u16* wprojT = (u16*)(ws + 23068672);   // [1024][1024]
  u16* V      = (u16*)(ws + 25165824);   // [4][16][2048][64]
  // Q and K live in d_out (33.5 MB fp32 = exactly 2 x 16.8 MB bf16); proj overwrites at the end
  u16* Q = (u16*)d_out;
  u16* K = Q + 8388608;

  cvt_bf16_kernel<<<4096, 256, 0, stream>>>(x, xb, 1048576);
  transpose_bf16_kernel<<<dim3(96, 32), 256, 0, stream>>>(w_qkv, wqkvT, 1024, 3072);
  transpose_bf16_kernel<<<dim3(32, 32), 256, 0, stream>>>(w_proj, wprojT, 1024, 1024);
  gemm_kernel<0><<<dim3(24, 64), 256, 0, stream>>>(xb, wqkvT, b_qkv, nullptr, Q, K, V,
                                                   8192, 3072, 1024);
  attn_kernel<<<dim3(16, 64), 256, 0, stream>>>(Q, K, V, xb);
  gemm_kernel<1><<<dim3(8, 64), 256, 0, stream>>>(xb, wprojT, b_proj, out,
                                                  nullptr, nullptr, nullptr, 8192, 1024, 1024);
}

// Round 3
// 372.851 us; speedup vs baseline: 1.2334x; 1.2334x over previous
//
#include <hip/hip_runtime.h>

typedef unsigned short u16;
typedef unsigned int u32;
typedef __attribute__((ext_vector_type(8))) short short8;
typedef __attribute__((ext_vector_type(4))) float f32x4;
typedef __attribute__((ext_vector_type(2))) unsigned int u32x2;

__device__ __forceinline__ u16 f32_to_bf16(float f) {
  u32 u = __builtin_bit_cast(u32, f);
  u += 0x7fffu + ((u >> 16) & 1u);  // RNE
  return (u16)(u >> 16);
}

__device__ __forceinline__ u32 cvt_pk_bf16(float a, float b) {
  u32 r;
  asm("v_cvt_pk_bf16_f32 %0, %1, %2" : "=v"(r) : "v"(a), "v"(b));
  return r;  // low16 = bf16(a), high16 = bf16(b)
}

__device__ __forceinline__ void gload16(const void* g, void* l) {
  __builtin_amdgcn_global_load_lds((const __attribute__((address_space(1))) u32*)g,
                                   (__attribute__((address_space(3))) u32*)l, 16, 0, 0);
}

// ---------------- x (fp32) -> bf16, 8 elems/thread ----------------
__global__ __launch_bounds__(256) void cvt_bf16_kernel(const float* __restrict__ in,
                                                       u16* __restrict__ out, int n8) {
  int i = blockIdx.x * 256 + threadIdx.x;
  if (i >= n8) return;
  const float4* p = (const float4*)in + (size_t)i * 2;
  float4 a = p[0], b = p[1];
  int4 v;
  v.x = (int)f32_to_bf16(a.x) | ((int)f32_to_bf16(a.y) << 16);
  v.y = (int)f32_to_bf16(a.z) | ((int)f32_to_bf16(a.w) << 16);
  v.z = (int)f32_to_bf16(b.x) | ((int)f32_to_bf16(b.y) << 16);
  v.w = (int)f32_to_bf16(b.z) | ((int)f32_to_bf16(b.w) << 16);
  *(int4*)(out + (size_t)i * 8) = v;
}

// ------------- fp32 [R][C] -> bf16 [C][R] (weights, one-time) -------------
__global__ __launch_bounds__(256) void transpose_bf16_kernel(const float* __restrict__ in,
                                                             u16* __restrict__ out, int R, int C) {
  __shared__ u16 tile[32][33];
  int tx = threadIdx.x & 31, ty = threadIdx.x >> 5;  // 32 x 8
  int c0 = blockIdx.x * 32, r0 = blockIdx.y * 32;
#pragma unroll
  for (int j = 0; j < 32; j += 8)
    tile[ty + j][tx] = f32_to_bf16(in[(size_t)(r0 + ty + j) * C + c0 + tx]);
  __syncthreads();
#pragma unroll
  for (int j = 0; j < 32; j += 8)
    out[(size_t)(c0 + ty + j) * R + r0 + tx] = tile[tx][ty + j];
}

// ---------------- bf16 GEMM (m97 structure): C = A[M][K] * Bt[N][K]^T + bias ----------------
// MODE 0: scatter Q,K as [B][H][S][64] bf16; V as [B][H][64][S] (transposed)
// MODE 1: fp32 out [M][N]
template <int MODE>
__global__ __launch_bounds__(256) void gemm_kernel(
    const u16* __restrict__ A, const u16* __restrict__ Bt, const float* __restrict__ bias,
    float* __restrict__ outf, u16* __restrict__ qo, u16* __restrict__ ko, u16* __restrict__ vo,
    int M, int N, int K) {
  __shared__ u16 Al[128 * 32];  // linear [row][32] (64B rows) -- global_load_lds dest
  __shared__ u16 Bl[128 * 32];
  int tid = threadIdx.x;
  int bm = blockIdx.y * 128, bn = blockIdx.x * 128;
  int lane = tid & 63, wid = tid >> 6;
  int lo = lane & 15, hi = lane >> 4;
  int wm = (wid >> 1) * 64, wn = (wid & 1) * 64;
  int srow = lane >> 2, schk = lane & 3;  // 16 rows x 4 chunks per 1KB load
  const u16* as0 = A + (size_t)(bm + wid * 32 + srow) * K + schk * 8;
  const u16* as1 = as0 + (size_t)16 * K;
  const u16* bs0 = Bt + (size_t)(bn + wid * 32 + srow) * K + schk * 8;
  const u16* bs1 = bs0 + (size_t)16 * K;
  u16* ad0 = &Al[wid * 32 * 32];
  u16* ad1 = ad0 + 512;
  u16* bd0 = &Bl[wid * 32 * 32];
  u16* bd1 = bd0 + 512;

  f32x4 acc[4][4] = {};
  for (int k0 = 0; k0 < K; k0 += 32) {
    __syncthreads();
    gload16(as0 + k0, ad0);
    gload16(as1 + k0, ad1);
    gload16(bs0 + k0, bd0);
    gload16(bs1 + k0, bd1);
    __syncthreads();
    short8 af[4], bfr[4];
#pragma unroll
    for (int mi = 0; mi < 4; ++mi) af[mi] = *(const short8*)&Al[(wm + mi * 16 + lo) * 32 + hi * 8];
#pragma unroll
    for (int ni = 0; ni < 4; ++ni) bfr[ni] = *(const short8*)&Bl[(wn + ni * 16 + lo) * 32 + hi * 8];
#pragma unroll
    for (int mi = 0; mi < 4; ++mi)
#pragma unroll
      for (int ni = 0; ni < 4; ++ni)
        acc[mi][ni] = __builtin_amdgcn_mfma_f32_16x16x32_bf16(af[mi], bfr[ni], acc[mi][ni], 0, 0, 0);
  }

#pragma unroll
  for (int mi = 0; mi < 4; ++mi)
#pragma unroll
    for (int ni = 0; ni < 4; ++ni) {
      int col = bn + wn + ni * 16 + lo;
      float bv = bias[col];
#pragma unroll
      for (int r = 0; r < 4; ++r) {
        int row = bm + wm + mi * 16 + hi * 4 + r;
        float val = acc[mi][ni][r] + bv;
        if (MODE == 1) {
          outf[(size_t)row * N + col] = val;
        } else {
          int part = col >> 10, rem = col & 1023;
          int h = rem >> 6, d = rem & 63;
          int b = row >> 11, s = row & 2047;
          if (part == 0)
            qo[((size_t)(b * 16 + h) * 2048 + s) * 64 + d] = f32_to_bf16(val);
          else if (part == 1)
            ko[((size_t)(b * 16 + h) * 2048 + s) * 64 + d] = f32_to_bf16(val);
          else
            vo[((size_t)(b * 16 + h) * 64 + d) * 2048 + s] = f32_to_bf16(val);  // transposed
        }
      }
    }
}

// ---------------- flash attention (swapped QK^T, in-lane softmax) ----------------
// grid: (16 q-tiles, 64 bh). 4 waves; 128 q/block (32/wave); KV tile 64; dh=64.
__global__ __launch_bounds__(256, 4) void attn_kernel(const u16* __restrict__ Qg,
                                                      const u16* __restrict__ Kg,
                                                      const u16* __restrict__ Vtg,
                                                      u16* __restrict__ ctx) {
  __shared__ u16 Ks[64 * 64];   // [key][d], XOR-swizzled 16B chunks
  __shared__ u16 Vs[64 * 64];   // [d][key], XOR-swizzled
  __shared__ u16 Ub[4 * 32 * 72];  // Q staging [128][64] first, then per-wave P [32][72]
  const int tid = threadIdx.x;
  const int lane = tid & 63, wid = tid >> 6;
  const int lo = lane & 15, hi = lane >> 4;
  const int qb = blockIdx.x, bh = blockIdx.y;
  const u16* Qh = Qg + (size_t)bh * (2048 * 64);
  const u16* Kh = Kg + (size_t)bh * (2048 * 64);
  const u16* Vh = Vtg + (size_t)bh * (64 * 2048);

  const int srow = lane >> 3;               // 0..7
  const int schk = (lane & 7) ^ srow;       // pre-swizzled source chunk

  // ---- stage Q [128][64] via global_load_lds (4 x 1KB per wave) ----
#pragma unroll
  for (int j = 0; j < 4; ++j) {
    int r = wid * 32 + j * 8 + srow;
    gload16(Qh + (size_t)(qb * 128 + r) * 64 + schk * 8, &Ub[(wid * 32 + j * 8) * 64]);
  }
  __syncthreads();
  short8 qf[2][2];  // B-frag: q rows
#pragma unroll
  for (int ni = 0; ni < 2; ++ni)
#pragma unroll
    for (int kk = 0; kk < 2; ++kk) {
      int r = wid * 32 + ni * 16 + lo;
      qf[ni][kk] = *(const short8*)&Ub[r * 64 + (((kk * 4 + hi) ^ (lo & 7)) * 8)];
    }

  const u16* ksrc = Kh + (size_t)(wid * 16 + srow) * 64 + schk * 8;
  const u16* vsrc = Vh + (size_t)(wid * 16 + srow) * 2048 + schk * 8;
  u16* kdst = &Ks[(wid * 16) * 64];
  u16* vdst = &Vs[(wid * 16) * 64];

  const short8 ONES = {0x3F80, 0x3F80, 0x3F80, 0x3F80, 0x3F80, 0x3F80, 0x3F80, 0x3F80};
  f32x4 o[2][4] = {};
  f32x4 lst[2] = {};
  float msx0 = -3.0e38f, msx1 = -3.0e38f;
  const float C = 0.18033688f;  // 0.125 * log2(e)
  const int wpb = wid * 2304;   // per-wave P base (elems)

  for (int kt = 0; kt < 32; ++kt) {
    __syncthreads();
    gload16(ksrc + (size_t)kt * 4096, kdst);
    gload16(ksrc + (size_t)kt * 4096 + 512, kdst + 512);
    gload16(vsrc + (size_t)kt * 64, vdst);
    gload16(vsrc + (size_t)kt * 64 + 8 * 2048, vdst + 512);
    __syncthreads();

    // S^T = K Q^T : sa[mi][ni] = S[q=ni*16+lo][k=mi*16+hi*4+r]
    f32x4 sa[4][2] = {};
#pragma unroll
    for (int kk = 0; kk < 2; ++kk) {
      short8 kf[4];
#pragma unroll
      for (int mi = 0; mi < 4; ++mi)
        kf[mi] = *(const short8*)&Ks[(mi * 16 + lo) * 64 + (((kk * 4 + hi) ^ (lo & 7)) * 8)];
#pragma unroll
      for (int mi = 0; mi < 4; ++mi)
#pragma unroll
        for (int ni = 0; ni < 2; ++ni)
          sa[mi][ni] = __builtin_amdgcn_mfma_f32_16x16x32_bf16(kf[mi], qf[ni][kk], sa[mi][ni], 0, 0, 0);
    }

    // per-q max: 16 in-lane values + 2 shfl (across hi groups)
    float mx0 = fmaxf(fmaxf(sa[0][0][0], sa[0][0][1]), fmaxf(sa[0][0][2], sa[0][0][3]));
    float mx1 = fmaxf(fmaxf(sa[0][1][0], sa[0][1][1]), fmaxf(sa[0][1][2], sa[0][1][3]));
#pragma unroll
    for (int mi = 1; mi < 4; ++mi) {
      mx0 = fmaxf(mx0, fmaxf(fmaxf(sa[mi][0][0], sa[mi][0][1]), fmaxf(sa[mi][0][2], sa[mi][0][3])));
      mx1 = fmaxf(mx1, fmaxf(fmaxf(sa[mi][1][0], sa[mi][1][1]), fmaxf(sa[mi][1][2], sa[mi][1][3])));
    }
    mx0 = fmaxf(mx0, __shfl_xor(mx0, 16, 64));
    mx0 = fmaxf(mx0, __shfl_xor(mx0, 32, 64));
    mx1 = fmaxf(mx1, __shfl_xor(mx1, 16, 64));
    mx1 = fmaxf(mx1, __shfl_xor(mx1, 32, 64));

    // defer-max: rescale only when max grows > 64 raw (= e^8 in exp units)
    int grow = (mx0 > msx0 + 64.f) | (mx1 > msx1 + 64.f);
    if (__any(grow)) {
      float mn0 = fmaxf(msx0, mx0), mn1 = fmaxf(msx1, mx1);
      float c0 = exp2f((msx0 - mn0) * C), c1 = exp2f((msx1 - mn1) * C);
      msx0 = mn0;
      msx1 = mn1;
#pragma unroll
      for (int qi = 0; qi < 2; ++qi)
#pragma unroll
        for (int r = 0; r < 4; ++r) {
          float cf = __shfl(qi == 0 ? c0 : c1, hi * 4 + r, 64);
          lst[qi][r] *= cf;
#pragma unroll
          for (int di = 0; di < 4; ++di) o[qi][di][r] *= cf;
        }
    }
    float mc0 = msx0 * C, mc1 = msx1 * C;
#pragma unroll
    for (int mi = 0; mi < 4; ++mi)
#pragma unroll
      for (int ni = 0; ni < 2; ++ni)
#pragma unroll
        for (int r = 0; r < 4; ++r)
          sa[mi][ni][r] = exp2f(__builtin_fmaf(sa[mi][ni][r], C, ni ? -mc1 : -mc0));

    // pack P -> bf16, write per-wave LDS [q=32][72] (k-pairs are register-adjacent)
#pragma unroll
    for (int mi = 0; mi < 4; ++mi)
#pragma unroll
      for (int ni = 0; ni < 2; ++ni) {
        u32x2 w;
        w.x = cvt_pk_bf16(sa[mi][ni][0], sa[mi][ni][1]);
        w.y = cvt_pk_bf16(sa[mi][ni][2], sa[mi][ni][3]);
        *(u32x2*)&Ub[wpb + (ni * 16 + lo) * 72 + mi * 16 + hi * 4] = w;
      }
    asm volatile("s_waitcnt lgkmcnt(0)" ::: "memory");
    __builtin_amdgcn_sched_barrier(0);

    // O += P V ; l += rowsum(P) via ones-MFMA (lands in o-layout)
    f32x4 tl[2] = {};
#pragma unroll
    for (int kk2 = 0; kk2 < 2; ++kk2) {
      short8 pf[2], vf[4];
#pragma unroll
      for (int qi = 0; qi < 2; ++qi)
        pf[qi] = *(const short8*)&Ub[wpb + (qi * 16 + lo) * 72 + kk2 * 32 + hi * 8];
#pragma unroll
      for (int di = 0; di < 4; ++di)
        vf[di] = *(const short8*)&Vs[(di * 16 + lo) * 64 + (((kk2 * 4 + hi) ^ (lo & 7)) * 8)];
#pragma unroll
      for (int qi = 0; qi < 2; ++qi)
        tl[qi] = __builtin_amdgcn_mfma_f32_16x16x32_bf16(pf[qi], ONES, tl[qi], 0, 0, 0);
#pragma unroll
      for (int qi = 0; qi < 2; ++qi)
#pragma unroll
        for (int di = 0; di < 4; ++di)
          o[qi][di] = __builtin_amdgcn_mfma_f32_16x16x32_bf16(pf[qi], vf[di], o[qi][di], 0, 0, 0);
    }
    lst[0] += tl[0];
    lst[1] += tl[1];
  }

  // epilogue: normalize, write ctx bf16 [B*S][1024]
  int b = bh >> 4, h = bh & 15;
#pragma unroll
  for (int qi = 0; qi < 2; ++qi)
#pragma unroll
    for (int r = 0; r < 4; ++r) {
      float inv = __builtin_amdgcn_rcpf(lst[qi][r]);
      int sr = qb * 128 + wid * 32 + qi * 16 + hi * 4 + r;
      u16* crow = ctx + (size_t)(b * 2048 + sr) * 1024 + h * 64;
#pragma unroll
      for (int di = 0; di < 4; ++di) crow[di * 16 + lo] = f32_to_bf16(o[qi][di][r] * inv);
    }
}

extern "C" void kernel_launch(void* const* d_in, const int* in_sizes, int n_in,
                              void* d_out, int out_size, void* d_ws, size_t ws_size,
                              hipStream_t stream) {
  const float* x      = (const float*)d_in[0];
  const float* w_qkv  = (const float*)d_in[1];
  const float* b_qkv  = (const float*)d_in[2];
  const float* w_proj = (const float*)d_in[3];
  const float* b_proj = (const float*)d_in[4];
  float* out = (float*)d_out;
  char* ws = (char*)d_ws;

  // ws layout (40 MB): xb/ctx alias 16.8M | wqkvT 6.3M | wprojT 2.1M | Vt 16.8M
  u16* xb     = (u16*)(ws);              // x bf16 [8192][1024]; later reused as ctx
  u16* wqkvT  = (u16*)(ws + 16777216);   // [3072][1024]
  u16* wprojT = (u16*)(ws + 23068672);   // [1024][1024]
  u16* Vt     = (u16*)(ws + 25165824);   // [4][16][64][2048]  (transposed)
  // Q and K live in d_out (33.5 MB fp32 = exactly 2 x 16.8 MB bf16); proj overwrites at the end
  u16* Q = (u16*)d_out;
  u16* K = Q + 8388608;

  cvt_bf16_kernel<<<4096, 256, 0, stream>>>(x, xb, 1048576);
  transpose_bf16_kernel<<<dim3(96, 32), 256, 0, stream>>>(w_qkv, wqkvT, 1024, 3072);
  transpose_bf16_kernel<<<dim3(32, 32), 256, 0, stream>>>(w_proj, wprojT, 1024, 1024);
  gemm_kernel<0><<<dim3(24, 64), 256, 0, stream>>>(xb, wqkvT, b_qkv, nullptr, Q, K, Vt,
                                                   8192, 3072, 1024);
  attn_kernel<<<dim3(16, 64), 256, 0, stream>>>(Q, K, Vt, xb);
  gemm_kernel<1><<<dim3(8, 64), 256, 0, stream>>>(xb, wprojT, b_proj, out,
                                                  nullptr, nullptr, nullptr, 8192, 1024, 1024);
}

// Round 5
// 291.750 us; speedup vs baseline: 1.5762x; 1.2780x over previous
//
#include <hip/hip_runtime.h>

typedef unsigned short u16;
typedef unsigned int u32;
typedef __attribute__((ext_vector_type(8))) short short8;
typedef __attribute__((ext_vector_type(4))) float f32x4;
typedef __attribute__((ext_vector_type(2))) unsigned int u32x2;

extern "C" __device__ float __ocml_native_exp2_f32(float);  // v_exp_f32

__device__ __forceinline__ u16 f32_to_bf16(float f) {
  u32 u = __builtin_bit_cast(u32, f);
  u += 0x7fffu + ((u >> 16) & 1u);  // RNE
  return (u16)(u >> 16);
}

__device__ __forceinline__ u32 cvt_pk_bf16(float a, float b) {
  u32 r;
  asm("v_cvt_pk_bf16_f32 %0, %1, %2" : "=v"(r) : "v"(a), "v"(b));
  return r;  // low16 = bf16(a), high16 = bf16(b)
}

__device__ __forceinline__ void gload16(const void* g, void* l) {
  __builtin_amdgcn_global_load_lds((const __attribute__((address_space(1))) u32*)g,
                                   (__attribute__((address_space(3))) u32*)l, 16, 0, 0);
}

// ---------------- x (fp32) -> bf16, 8 elems/thread ----------------
__global__ __launch_bounds__(256) void cvt_bf16_kernel(const float* __restrict__ in,
                                                       u16* __restrict__ out, int n8) {
  int i = blockIdx.x * 256 + threadIdx.x;
  if (i >= n8) return;
  const float4* p = (const float4*)in + (size_t)i * 2;
  float4 a = p[0], b = p[1];
  int4 v;
  v.x = (int)f32_to_bf16(a.x) | ((int)f32_to_bf16(a.y) << 16);
  v.y = (int)f32_to_bf16(a.z) | ((int)f32_to_bf16(a.w) << 16);
  v.z = (int)f32_to_bf16(b.x) | ((int)f32_to_bf16(b.y) << 16);
  v.w = (int)f32_to_bf16(b.z) | ((int)f32_to_bf16(b.w) << 16);
  *(int4*)(out + (size_t)i * 8) = v;
}

// ------------- fp32 [R][C] -> bf16 [C][R] (weights, one-time) -------------
__global__ __launch_bounds__(256) void transpose_bf16_kernel(const float* __restrict__ in,
                                                             u16* __restrict__ out, int R, int C) {
  __shared__ u16 tile[32][33];
  int tx = threadIdx.x & 31, ty = threadIdx.x >> 5;  // 32 x 8
  int c0 = blockIdx.x * 32, r0 = blockIdx.y * 32;
#pragma unroll
  for (int j = 0; j < 32; j += 8)
    tile[ty + j][tx] = f32_to_bf16(in[(size_t)(r0 + ty + j) * C + c0 + tx]);
  __syncthreads();
#pragma unroll
  for (int j = 0; j < 32; j += 8)
    out[(size_t)(c0 + ty + j) * R + r0 + tx] = tile[tx][ty + j];
}

// ---------------- bf16 GEMM (2-phase prefetch): C = A[M][K] * Bt[N][K]^T + bias -------
// MODE 0: scatter Q,K as [B][H][S][64] bf16; V via LDS-transpose as [B][H][64][S]
// MODE 1: fp32 out [M][N]
template <int MODE>
__global__ __launch_bounds__(256) void gemm_kernel(
    const u16* __restrict__ A, const u16* __restrict__ Bt, const float* __restrict__ bias,
    float* __restrict__ outf, u16* __restrict__ qo, u16* __restrict__ ko, u16* __restrict__ vo,
    int M, int N, int K) {
  __shared__ u16 Sm[2][2][4096];  // [dbuf][A,B][128*32]  32KB
  const int tid = threadIdx.x;
  const int id = blockIdx.y * gridDim.x + blockIdx.x;
  const int nwg = gridDim.x * gridDim.y;                 // multiple of 8
  const int swz = (id & 7) * (nwg >> 3) + (id >> 3);     // XCD-chunked, bijective
  const int bn = (swz % gridDim.x) * 128;
  const int bm = (swz / gridDim.x) * 128;
  const int lane = tid & 63, wid = tid >> 6;
  const int lo = lane & 15, hi = lane >> 4;
  const int wm = (wid >> 1) * 64, wn = (wid & 1) * 64;
  const int srow = lane >> 2, schk = lane & 3;  // 16 rows x 4 chunks per 1KB load
  const u16* as0 = A + (size_t)(bm + wid * 32 + srow) * K + schk * 8;
  const u16* bs0 = Bt + (size_t)(bn + wid * 32 + srow) * K + schk * 8;
  const size_t row16 = (size_t)16 * K;

  f32x4 acc[4][4] = {};
  // prologue stage into buf 0
  gload16(as0, &Sm[0][0][wid * 1024]);
  gload16(as0 + row16, &Sm[0][0][wid * 1024 + 512]);
  gload16(bs0, &Sm[0][1][wid * 1024]);
  gload16(bs0 + row16, &Sm[0][1][wid * 1024 + 512]);
  int cur = 0;
  for (int k0 = 0; k0 < K; k0 += 32) {
    __syncthreads();  // buf[cur] ready (compiler drains vmcnt before barrier)
    if (k0 + 32 < K) {
      int nx = cur ^ 1;
      gload16(as0 + k0 + 32, &Sm[nx][0][wid * 1024]);
      gload16(as0 + k0 + 32 + row16, &Sm[nx][0][wid * 1024 + 512]);
      gload16(bs0 + k0 + 32, &Sm[nx][1][wid * 1024]);
      gload16(bs0 + k0 + 32 + row16, &Sm[nx][1][wid * 1024 + 512]);
    }
    const u16* Al = Sm[cur][0];
    const u16* Bl = Sm[cur][1];
    short8 af[4], bfr[4];
#pragma unroll
    for (int mi = 0; mi < 4; ++mi) af[mi] = *(const short8*)&Al[(wm + mi * 16 + lo) * 32 + hi * 8];
#pragma unroll
    for (int ni = 0; ni < 4; ++ni) bfr[ni] = *(const short8*)&Bl[(wn + ni * 16 + lo) * 32 + hi * 8];
#pragma unroll
    for (int mi = 0; mi < 4; ++mi)
#pragma unroll
      for (int ni = 0; ni < 4; ++ni)
        acc[mi][ni] = __builtin_amdgcn_mfma_f32_16x16x32_bf16(af[mi], bfr[ni], acc[mi][ni], 0, 0, 0);
    cur ^= 1;
  }

  if (MODE == 0 && bn >= 2048) {
    // ---- V epilogue: LDS transpose (2 half-passes of 64 cols), coalesced stores ----
    u16* T = &Sm[0][0][0];  // [64 cols][136 rows] u16 = 17408B
    const int b = bm >> 11;
    const int sbase = bm & 2047;
#pragma unroll
    for (int hh = 0; hh < 2; ++hh) {
      __syncthreads();  // all frag reads / prior pass reads done
      if (wn == hh * 64) {
#pragma unroll
        for (int ni = 0; ni < 4; ++ni) {
          int c = ni * 16 + lo;
          float bv = bias[bn + hh * 64 + c];
#pragma unroll
          for (int mi = 0; mi < 4; ++mi) {
            u32* dst = (u32*)&T[c * 136 + wm + mi * 16 + hi * 4];
            dst[0] = cvt_pk_bf16(acc[mi][ni][0] + bv, acc[mi][ni][1] + bv);
            dst[1] = cvt_pk_bf16(acc[mi][ni][2] + bv, acc[mi][ni][3] + bv);
          }
        }
      }
      __syncthreads();
      int h = ((bn - 2048) >> 6) + hh;
#pragma unroll
      for (int p = 0; p < 4; ++p) {
        int unit = p * 256 + tid;
        int c = unit >> 4, chunk = unit & 15;
        short8 v = *(const short8*)&T[c * 136 + chunk * 8];
        *(short8*)&vo[((size_t)((b * 16 + h) * 64 + c)) * 2048 + sbase + chunk * 8] = v;
      }
    }
  } else {
#pragma unroll
    for (int mi = 0; mi < 4; ++mi)
#pragma unroll
      for (int ni = 0; ni < 4; ++ni) {
        int col = bn + wn + ni * 16 + lo;
        float bv = bias[col];
#pragma unroll
        for (int r = 0; r < 4; ++r) {
          int row = bm + wm + mi * 16 + hi * 4 + r;
          float val = acc[mi][ni][r] + bv;
          if (MODE == 1) {
            outf[(size_t)row * N + col] = val;
          } else {
            int part = col >> 10, rem = col & 1023;
            int h = rem >> 6, d = rem & 63;
            int b = row >> 11, s = row & 2047;
            if (part == 0)
              qo[((size_t)(b * 16 + h) * 2048 + s) * 64 + d] = f32_to_bf16(val);
            else
              ko[((size_t)(b * 16 + h) * 2048 + s) * 64 + d] = f32_to_bf16(val);
          }
        }
      }
  }
}

// ---------------- flash attention (swapped QK^T, prefetch double-buffer) ----------------
// grid: 1024 blocks (16 q-tiles x 64 bh, XCD-swizzled). 4 waves; 128 q/block; KV tile 64.
__global__ __launch_bounds__(256, 3) void attn_kernel(const u16* __restrict__ Qg,
                                                      const u16* __restrict__ Kg,
                                                      const u16* __restrict__ Vtg,
                                                      u16* __restrict__ ctx) {
  __shared__ u16 KV[2][2][4096];  // [dbuf][K,V][64*64] 32KB
  __shared__ u16 Pb[4][2304];     // per-wave P [32][72] 18.4KB
  const int tid = threadIdx.x;
  const int lane = tid & 63, wid = tid >> 6;
  const int lo = lane & 15, hi = lane >> 4;
  const int id = blockIdx.y * gridDim.x + blockIdx.x;  // 1024
  const int swz = (id & 7) * 128 + (id >> 3);          // XCD0 -> bh 0..7 (4MB KV = L2)
  const int qb = swz & 15, bh = swz >> 4;
  const u16* Qh = Qg + (size_t)bh * (2048 * 64);
  const u16* Kh = Kg + (size_t)bh * (2048 * 64);
  const u16* Vh = Vtg + (size_t)bh * (64 * 2048);

  // Q fragments: direct global->reg (B-frag rows = q)
  short8 qf[2][2];
#pragma unroll
  for (int ni = 0; ni < 2; ++ni)
#pragma unroll
    for (int kk = 0; kk < 2; ++kk)
      qf[ni][kk] = *(const short8*)&Qh[(size_t)(qb * 128 + wid * 32 + ni * 16 + lo) * 64 +
                                       kk * 32 + hi * 8];

  const int srow = lane >> 3;          // 0..7
  const int schk = (lane & 7) ^ srow;  // pre-swizzled source chunk (matches read XOR)
  const u16* ksrc = Kh + (size_t)(wid * 16 + srow) * 64 + schk * 8;
  const u16* vsrc = Vh + (size_t)(wid * 16 + srow) * 2048 + schk * 8;

  const short8 ONES = {0x3F80, 0x3F80, 0x3F80, 0x3F80, 0x3F80, 0x3F80, 0x3F80, 0x3F80};
  f32x4 o[2][4] = {};
  f32x4 lst[2] = {};
  float msx0 = -3.0e38f, msx1 = -3.0e38f;
  const float C = 0.18033688f;  // 0.125 * log2(e)

#define STAGE(buf, kt)                                                     \
  do {                                                                     \
    gload16(ksrc + (size_t)(kt) * 4096, &KV[buf][0][wid * 1024]);          \
    gload16(ksrc + (size_t)(kt) * 4096 + 512, &KV[buf][0][wid * 1024 + 512]); \
    gload16(vsrc + (size_t)(kt) * 64, &KV[buf][1][wid * 1024]);            \
    gload16(vsrc + (size_t)(kt) * 64 + 8 * 2048, &KV[buf][1][wid * 1024 + 512]); \
  } while (0)

  STAGE(0, 0);
  int cur = 0;
  for (int kt = 0; kt < 32; ++kt) {
    __syncthreads();  // buf[cur] ready; prefetch from iter t-1 drained here
    if (kt < 31) STAGE(cur ^ 1, kt + 1);
    const u16* Ks = KV[cur][0];
    const u16* Vs = KV[cur][1];

    // S^T = K Q^T : sa[mi][ni] = S[q=ni*16+lo][k=mi*16+hi*4+r]
    f32x4 sa[4][2] = {};
#pragma unroll
    for (int kk = 0; kk < 2; ++kk) {
      short8 kf[4];
#pragma unroll
      for (int mi = 0; mi < 4; ++mi)
        kf[mi] = *(const short8*)&Ks[(mi * 16 + lo) * 64 + (((kk * 4 + hi) ^ (lo & 7)) * 8)];
      __builtin_amdgcn_s_setprio(1);
#pragma unroll
      for (int mi = 0; mi < 4; ++mi)
#pragma unroll
        for (int ni = 0; ni < 2; ++ni)
          sa[mi][ni] = __builtin_amdgcn_mfma_f32_16x16x32_bf16(kf[mi], qf[ni][kk], sa[mi][ni], 0, 0, 0);
      __builtin_amdgcn_s_setprio(0);
    }

    // per-q max: 16 in-lane values + 2 shfl
    float mx0 = fmaxf(fmaxf(sa[0][0][0], sa[0][0][1]), fmaxf(sa[0][0][2], sa[0][0][3]));
    float mx1 = fmaxf(fmaxf(sa[0][1][0], sa[0][1][1]), fmaxf(sa[0][1][2], sa[0][1][3]));
#pragma unroll
    for (int mi = 1; mi < 4; ++mi) {
      mx0 = fmaxf(mx0, fmaxf(fmaxf(sa[mi][0][0], sa[mi][0][1]), fmaxf(sa[mi][0][2], sa[mi][0][3])));
      mx1 = fmaxf(mx1, fmaxf(fmaxf(sa[mi][1][0], sa[mi][1][1]), fmaxf(sa[mi][1][2], sa[mi][1][3])));
    }
    mx0 = fmaxf(mx0, __shfl_xor(mx0, 16, 64));
    mx0 = fmaxf(mx0, __shfl_xor(mx0, 32, 64));
    mx1 = fmaxf(mx1, __shfl_xor(mx1, 16, 64));
    mx1 = fmaxf(mx1, __shfl_xor(mx1, 32, 64));

    // defer-max: rescale only when raw max grows > 64 (= e^8 in exp units)
    int grow = (mx0 > msx0 + 64.f) | (mx1 > msx1 + 64.f);
    if (__any(grow)) {
      float mn0 = fmaxf(msx0, mx0), mn1 = fmaxf(msx1, mx1);
      float c0 = __ocml_native_exp2_f32((msx0 - mn0) * C);
      float c1 = __ocml_native_exp2_f32((msx1 - mn1) * C);
      msx0 = mn0;
      msx1 = mn1;
#pragma unroll
      for (int qi = 0; qi < 2; ++qi)
#pragma unroll
        for (int r = 0; r < 4; ++r) {
          float cf = __shfl(qi == 0 ? c0 : c1, hi * 4 + r, 64);
          lst[qi][r] *= cf;
#pragma unroll
          for (int di = 0; di < 4; ++di) o[qi][di][r] *= cf;
        }
    }
    float mc0 = msx0 * C, mc1 = msx1 * C;
#pragma unroll
    for (int mi = 0; mi < 4; ++mi)
#pragma unroll
      for (int ni = 0; ni < 2; ++ni)
#pragma unroll
        for (int r = 0; r < 4; ++r)
          sa[mi][ni][r] = __ocml_native_exp2_f32(__builtin_fmaf(sa[mi][ni][r], C, ni ? -mc1 : -mc0));

    // pack P -> bf16 into per-wave LDS [q=32][72]
#pragma unroll
    for (int mi = 0; mi < 4; ++mi)
#pragma unroll
      for (int ni = 0; ni < 2; ++ni) {
        u32x2 w;
        w.x = cvt_pk_bf16(sa[mi][ni][0], sa[mi][ni][1]);
        w.y = cvt_pk_bf16(sa[mi][ni][2], sa[mi][ni][3]);
        *(u32x2*)&Pb[wid][(ni * 16 + lo) * 72 + mi * 16 + hi * 4] = w;
      }
    asm volatile("s_waitcnt lgkmcnt(0)" ::: "memory");
    __builtin_amdgcn_sched_barrier(0);

    // O += P V ; lst += rowsum(P) via ones-MFMA (accumulates in place)
#pragma unroll
    for (int kk2 = 0; kk2 < 2; ++kk2) {
      short8 pf[2], vf[4];
#pragma unroll
      for (int qi = 0; qi < 2; ++qi)
        pf[qi] = *(const short8*)&Pb[wid][(qi * 16 + lo) * 72 + kk2 * 32 + hi * 8];
#pragma unroll
      for (int di = 0; di < 4; ++di)
        vf[di] = *(const short8*)&Vs[(di * 16 + lo) * 64 + (((kk2 * 4 + hi) ^ (lo & 7)) * 8)];
      __builtin_amdgcn_s_setprio(1);
#pragma unroll
      for (int qi = 0; qi < 2; ++qi)
        lst[qi] = __builtin_amdgcn_mfma_f32_16x16x32_bf16(pf[qi], ONES, lst[qi], 0, 0, 0);
#pragma unroll
      for (int qi = 0; qi < 2; ++qi)
#pragma unroll
        for (int di = 0; di < 4; ++di)
          o[qi][di] = __builtin_amdgcn_mfma_f32_16x16x32_bf16(pf[qi], vf[di], o[qi][di], 0, 0, 0);
      __builtin_amdgcn_s_setprio(0);
    }
    cur ^= 1;
  }
#undef STAGE

  // epilogue: normalize, write ctx bf16 [B*S][1024]
  int b = bh >> 4, h = bh & 15;
#pragma unroll
  for (int qi = 0; qi < 2; ++qi)
#pragma unroll
    for (int r = 0; r < 4; ++r) {
      float inv = __builtin_amdgcn_rcpf(lst[qi][r]);
      int sr = qb * 128 + wid * 32 + qi * 16 + hi * 4 + r;
      u16* crow = ctx + (size_t)(b * 2048 + sr) * 1024 + h * 64;
#pragma unroll
      for (int di = 0; di < 4; ++di) crow[di * 16 + lo] = f32_to_bf16(o[qi][di][r] * inv);
    }
}

extern "C" void kernel_launch(void* const* d_in, const int* in_sizes, int n_in,
                              void* d_out, int out_size, void* d_ws, size_t ws_size,
                              hipStream_t stream) {
  const float* x      = (const float*)d_in[0];
  const float* w_qkv  = (const float*)d_in[1];
  const float* b_qkv  = (const float*)d_in[2];
  const float* w_proj = (const float*)d_in[3];
  const float* b_proj = (const float*)d_in[4];
  float* out = (float*)d_out;
  char* ws = (char*)d_ws;

  // ws layout (40 MB): xb/ctx alias 16.8M | wqkvT 6.3M | wprojT 2.1M | Vt 16.8M
  u16* xb     = (u16*)(ws);              // x bf16 [8192][1024]; later reused as ctx
  u16* wqkvT  = (u16*)(ws + 16777216);   // [3072][1024]
  u16* wprojT = (u16*)(ws + 23068672);   // [1024][1024]
  u16* Vt     = (u16*)(ws + 25165824);   // [4][16][64][2048]  (transposed)
  // Q and K live in d_out (33.5 MB fp32 = exactly 2 x 16.8 MB bf16); proj overwrites at the end
  u16* Q = (u16*)d_out;
  u16* K = Q + 8388608;

  cvt_bf16_kernel<<<4096, 256, 0, stream>>>(x, xb, 1048576);
  transpose_bf16_kernel<<<dim3(96, 32), 256, 0, stream>>>(w_qkv, wqkvT, 1024, 3072);
  transpose_bf16_kernel<<<dim3(32, 32), 256, 0, stream>>>(w_proj, wprojT, 1024, 1024);
  gemm_kernel<0><<<dim3(24, 64), 256, 0, stream>>>(xb, wqkvT, b_qkv, nullptr, Q, K, Vt,
                                                   8192, 3072, 1024);
  attn_kernel<<<dim3(16, 64), 256, 0, stream>>>(Q, K, Vt, xb);
  gemm_kernel<1><<<dim3(8, 64), 256, 0, stream>>>(xb, wprojT, b_proj, out,
                                                  nullptr, nullptr, nullptr, 8192, 1024, 1024);
}